// Round 14
// baseline (373.905 us; speedup 1.0000x reference)
//
#include <hip/hip_runtime.h>

typedef __attribute__((ext_vector_type(4))) float f32x4;
typedef __attribute__((ext_vector_type(8))) short bf16x8;

#define MFMA(a, b, c) __builtin_amdgcn_mfma_f32_16x16x32_bf16(a, b, c, 0, 0, 0)
// WAR-hazard shield (R13-proven): fence cluster, then 32 idle cycles before any
// subsequent load may write back onto MFMA source registers.
#define NOPS asm volatile("s_nop 7\ns_nop 7\ns_nop 7\ns_nop 7" ::: "memory")

static __device__ __forceinline__ short rnebf(float x) {
  union { float f; unsigned u; } v; v.f = x;
  return (short)((v.u + 0x7FFFu + ((v.u >> 16) & 1u)) >> 16);
}
static __device__ __forceinline__ float bf2f(short h) {
  union { unsigned u; float f; } v; v.u = ((unsigned)(unsigned short)h) << 16;
  return v.f;
}
// R14: RNE hi + RNE lo (unbiased, resid halved vs trunc-hi)
static __device__ __forceinline__ void split2(float x, short& hi, short& lo) {
  hi = rnebf(x);
  lo = rnebf(x - bf2f(hi));
}

// ---------------- prep: pack 8 weights as hi/lo B-fragments ----------------
__global__ void prep_w(const float* __restrict__ W0, const float* __restrict__ W1,
                       const float* __restrict__ W2, const float* __restrict__ W3,
                       const float* __restrict__ W4, const float* __restrict__ W5,
                       const float* __restrict__ W6, const float* __restrict__ W7,
                       short* __restrict__ ws) {
  const float* W[8] = {W0, W1, W2, W3, W4, W5, W6, W7};
  int t = blockIdx.x * 256 + threadIdx.x;
  int lane = t & 63, fragid = (t >> 6) & 7, mat = t >> 9;
  const float* Wm = W[mat];
  int ct = fragid >> 1, kh = fragid & 1;
  int wcol = ct * 16 + (lane & 15);
  int k0 = kh * 32 + ((lane >> 4) << 3);
  bf16x8 vh, vl;
#pragma unroll
  for (int j = 0; j < 8; ++j) {
    short h, l;
    split2(Wm[(k0 + j) * 64 + wcol], h, l);
    vh[j] = h; vl[j] = l;
  }
  size_t base = ((size_t)(mat * 16) + fragid) * 512 + lane * 8;
  *(bf16x8*)(ws + base) = vh;
  *(bf16x8*)(ws + base + 4096) = vl;
}

struct BF { bf16x8 h[4][2], l[4][2]; };

static __device__ __forceinline__ void loadB(const short* __restrict__ ws, int mat, int lane,
                                             BF& B) {
#pragma unroll
  for (int ct = 0; ct < 4; ++ct)
#pragma unroll
    for (int kh = 0; kh < 2; ++kh) {
      B.h[ct][kh] = *(const bf16x8*)(ws + ((size_t)(mat * 16) + ct * 2 + kh) * 512 + lane * 8);
      B.l[ct][kh] = *(const bf16x8*)(ws + ((size_t)(mat * 16 + 8) + ct * 2 + kh) * 512 + lane * 8);
    }
}

// fenced MFMA cluster (R13-proven)
static __device__ __forceinline__ void cluster(const bf16x8 (&ah)[2], const bf16x8 (&al)[2],
                                               const BF& B, f32x4 (&acc)[4]) {
  __builtin_amdgcn_sched_barrier(0);
#pragma unroll
  for (int ct = 0; ct < 4; ++ct)
#pragma unroll
    for (int kh = 0; kh < 2; ++kh) {
      acc[ct] = MFMA(ah[kh], B.h[ct][kh], acc[ct]);
      acc[ct] = MFMA(al[kh], B.h[ct][kh], acc[ct]);
      acc[ct] = MFMA(ah[kh], B.l[ct][kh], acc[ct]);
    }
  __builtin_amdgcn_sched_barrier(0);
  NOPS;
}

// ---- HW-verified (R6 diag): swizzled stride-64 plane load/store (plane = 8192 B) ----
static __device__ __forceinline__ void ldM(const short* __restrict__ M, int ph, int arow,
                                           int lane, bf16x8 (&ah)[2], bf16x8 (&al)[2]) {
  int swz = (arow & 7) << 4;
#pragma unroll
  for (int kh = 0; kh < 2; ++kh) {
    int ab = (arow * 128 + kh * 64 + ((lane >> 4) << 4)) ^ swz;
    ah[kh] = *(const bf16x8*)((const char*)M + ph * 8192 + ab);
    al[kh] = *(const bf16x8*)((const char*)M + (ph + 1) * 8192 + ab);
  }
}
static __device__ __forceinline__ void stM(short* __restrict__ M, int p, int n, int w, float x) {
  short h, l;
  split2(x, h, l);
  int ab = (n * 128 + w * 2) ^ ((n & 7) << 4);
  *(short*)((char*)M + p * 8192 + ab) = h;
  *(short*)((char*)M + (p + 1) * 8192 + ab) = l;
}

// ---------------- fused kernel: 64 rows/block, 256 threads ----------------
__global__ __launch_bounds__(256, 2) void fused_tp(
    const float* __restrict__ x1, const float* __restrict__ edge,
    const float* __restrict__ tp, const float* __restrict__ node,
    const short* __restrict__ ws, float* __restrict__ out) {
  __shared__ short lds_s[8 * 4096];   // 8 swizzled planes, 64 KB
  __shared__ float cst[64 * 6];
  const int t = threadIdx.x;
  const int R0 = blockIdx.x * 64;

  // ---- phase 0: stage x1 -> swizzled h/l planes (col-per-thread); consts ----
  {
    int c = t;
    int plane_hi, u;
    if (c < 64) { plane_hi = 0; u = c; }
    else { int q = c - 64; u = q / 3; int m = q - u * 3; plane_hi = 2 + 2 * m; }
    char* phi = (char*)lds_s + plane_hi * 8192;
    char* plo = phi + 8192;
    const float* xc = x1 + (size_t)R0 * 256 + c;
#pragma unroll 8
    for (int i = 0; i < 64; ++i) {
      short h, l;
      split2(xc[(size_t)i * 256], h, l);
      int ab = (i * 128 + u * 2) ^ ((i & 7) << 4);
      *(short*)(phi + ab) = h;
      *(short*)(plo + ab) = l;
    }
    if (t < 64) {
      f32x4 e = *(const f32x4*)(edge + (size_t)(R0 + t) * 4);
      float a = node[R0 + t];
      float* cr = cst + t * 6;
      cr[0] = e[0]; cr[1] = e[1]; cr[2] = e[2]; cr[3] = e[3];
      cr[4] = 0.125f * 0.08838834764831845f * a * a;  // kp
      cr[5] = 0.125f * a;                             // ksc
    }
  }
  __syncthreads();

  const int lane = t & 63;
  const int wid = t >> 6;
  const int r0 = wid * 16;
  const int lg = lane >> 4;
  const int arow = r0 + (lane & 15);
  const f32x4 z = {0.f, 0.f, 0.f, 0.f};

  // ---- stage 1: 8 GEMMs, double-buffered B ----
  f32x4 scs[4], s0v[4], scv[3][4], v0v[3][4];
#pragma unroll
  for (int ct = 0; ct < 4; ++ct) { scs[ct] = z; s0v[ct] = z; }
#pragma unroll
  for (int m = 0; m < 3; ++m)
#pragma unroll
    for (int ct = 0; ct < 4; ++ct) { scv[m][ct] = z; v0v[m][ct] = z; }
  {
    BF B0, B1;
    bf16x8 ah[2], al[2];
    loadB(ws, 0, lane, B0);                 // W_sc_s
    loadB(ws, 1, lane, B1);                 // W_lin0_s
    ldM(lds_s, 0, arow, lane, ah, al);      // s
    cluster(ah, al, B0, scs);
    loadB(ws, 2, lane, B0);                 // W_sc_v (overlaps next cluster)
    cluster(ah, al, B1, s0v);
    loadB(ws, 3, lane, B1);                 // W_lin0_v
#pragma unroll
    for (int m = 0; m < 3; ++m) {
      ldM(lds_s, 2 + 2 * m, arow, lane, ah, al);  // v_m
      cluster(ah, al, B0, scv[m]);
      cluster(ah, al, B1, v0v[m]);
    }
  }
  __syncthreads();

  // ---- phase 2a: mids mA->(0,1) mB->(2,3) mD->(4,5) ----
#pragma unroll
  for (int reg = 0; reg < 4; ++reg) {
    int n = r0 + (lg << 2) + reg;
    const float* cr = cst + n * 6;
    float e0 = cr[0], e1x = cr[1], e1y = cr[2], e1z = cr[3];
    const float* tr = tp + (size_t)(R0 + n) * 256;
#pragma unroll
    for (int ct = 0; ct < 4; ++ct) {
      int w = ct * 16 + (lane & 15);
      float s0 = s0v[ct][reg];
      float dot = v0v[0][ct][reg] * e1x + v0v[1][ct][reg] * e1y + v0v[2][ct][reg] * e1z;
      stM(lds_s, 0, n, w, tr[w] * s0 * e0);
      stM(lds_s, 2, n, w, tr[64 + w] * s0);
      stM(lds_s, 4, n, w, tr[192 + w] * dot * 0.5773502691896258f);
    }
  }
  __syncthreads();

  // ---- stage 2a: gAD = mA@W_A + mD@W_D ; gB = mB@W_B ----
  f32x4 gAD[4], gB[4];
#pragma unroll
  for (int ct = 0; ct < 4; ++ct) { gAD[ct] = z; gB[ct] = z; }
  {
    BF B0, B1;
    bf16x8 ah[2], al[2];
    loadB(ws, 4, lane, B0);                 // W_lin_A
    loadB(ws, 5, lane, B1);                 // W_lin_D
    ldM(lds_s, 0, arow, lane, ah, al);      // mA
    cluster(ah, al, B0, gAD);
    loadB(ws, 6, lane, B0);                 // W_lin_B
    ldM(lds_s, 4, arow, lane, ah, al);      // mD
    cluster(ah, al, B1, gAD);
    ldM(lds_s, 2, arow, lane, ah, al);      // mB
    cluster(ah, al, B0, gB);
  }

  // ---- early s-channel store (frees scs/gAD) ----
#pragma unroll
  for (int reg = 0; reg < 4; ++reg) {
    int n = r0 + (lg << 2) + reg;
    const float* cr = cst + n * 6;
    float kp = cr[4], ksc = cr[5];
    float* orow = out + (size_t)(R0 + n) * 256;
#pragma unroll
    for (int ct = 0; ct < 4; ++ct) {
      int w = ct * 16 + (lane & 15);
      orow[w] = kp * gAD[ct][reg] + ksc * scs[ct][reg];
    }
  }
  __syncthreads();

  // ---- phase 2b: mC x->(0,1) y->(2,3) z->(4,5) ----
#pragma unroll
  for (int reg = 0; reg < 4; ++reg) {
    int n = r0 + (lg << 2) + reg;
    float e0 = cst[n * 6];
    const float* tr = tp + (size_t)(R0 + n) * 256;
#pragma unroll
    for (int ct = 0; ct < 4; ++ct) {
      int w = ct * 16 + (lane & 15);
      float wc = tr[128 + w];
#pragma unroll
      for (int m = 0; m < 3; ++m) stM(lds_s, 2 * m, n, w, wc * v0v[m][ct][reg] * e0);
    }
  }
  __syncthreads();

  // ---- stage 2b: gC_m = mC_m @ W_C ----
  f32x4 gC[3][4];
#pragma unroll
  for (int m = 0; m < 3; ++m)
#pragma unroll
    for (int ct = 0; ct < 4; ++ct) gC[m][ct] = z;
  {
    BF B0;
    loadB(ws, 7, lane, B0);                 // W_lin_C
#pragma unroll
    for (int m = 0; m < 3; ++m) {
      bf16x8 ah[2], al[2];
      ldM(lds_s, 2 * m, arow, lane, ah, al);
      cluster(ah, al, B0, gC[m]);
    }
  }

  // ---- epilogue: v-channels ----
#pragma unroll
  for (int reg = 0; reg < 4; ++reg) {
    int n = r0 + (lg << 2) + reg;
    const float* cr = cst + n * 6;
    float e1x = cr[1], e1y = cr[2], e1z = cr[3], kp = cr[4], ksc = cr[5];
    float* orow = out + (size_t)(R0 + n) * 256;
#pragma unroll
    for (int ct = 0; ct < 4; ++ct) {
      int w = ct * 16 + (lane & 15);
      float vx = kp * (e1x * gB[ct][reg] + gC[0][ct][reg]) + ksc * scv[0][ct][reg];
      float vy = kp * (e1y * gB[ct][reg] + gC[1][ct][reg]) + ksc * scv[1][ct][reg];
      float vz = kp * (e1z * gB[ct][reg] + gC[2][ct][reg]) + ksc * scv[2][ct][reg];
      float* vp = orow + 64 + 3 * w;
      vp[0] = vx; vp[1] = vy; vp[2] = vz;
    }
  }
}

extern "C" void kernel_launch(void* const* d_in, const int* in_sizes, int n_in,
                              void* d_out, int out_size, void* d_ws, size_t ws_size,
                              hipStream_t stream) {
  const float* x1   = (const float*)d_in[0];
  const float* edge = (const float*)d_in[1];
  const float* tp   = (const float*)d_in[2];
  const float* node = (const float*)d_in[3];
  short* ws = (short*)d_ws;  // 128 KiB
  int n = in_sizes[0] / 256;

  // mats: 0=W_sc_s 1=W_lin0_s 2=W_sc_v 3=W_lin0_v 4=W_lin_A 5=W_lin_D 6=W_lin_B 7=W_lin_C
  prep_w<<<16, 256, 0, stream>>>(
      (const float*)d_in[6], (const float*)d_in[4],
      (const float*)d_in[7], (const float*)d_in[5],
      (const float*)d_in[8], (const float*)d_in[9],
      (const float*)d_in[10], (const float*)d_in[11], ws);

  fused_tp<<<n / 64, 256, 0, stream>>>(x1, edge, tp, node, ws, (float*)d_out);
}

// Round 15
// 202.080 us; speedup vs baseline: 1.8503x; 1.8503x over previous
//
#include <hip/hip_runtime.h>

typedef __attribute__((ext_vector_type(4))) float f32x4;
typedef __attribute__((ext_vector_type(8))) short bf16x8;

#define MFMA(a, b, c) __builtin_amdgcn_mfma_f32_16x16x32_bf16(a, b, c, 0, 0, 0)
// WAR-hazard shield (R13-proven)
#define NOPS asm volatile("s_nop 7\ns_nop 7\ns_nop 7\ns_nop 7" ::: "memory")

static __device__ __forceinline__ short rnebf(float x) {
  union { float f; unsigned u; } v; v.f = x;
  return (short)((v.u + 0x7FFFu + ((v.u >> 16) & 1u)) >> 16);
}
static __device__ __forceinline__ float bf2f(short h) {
  union { unsigned u; float f; } v; v.u = ((unsigned)(unsigned short)h) << 16;
  return v.f;
}
// RNE hi + RNE lo (R14-proven: absmax 0.71)
static __device__ __forceinline__ void split2(float x, short& hi, short& lo) {
  hi = rnebf(x);
  lo = rnebf(x - bf2f(hi));
}

// ---------------- prep: pack 8 weights as hi/lo B-fragments ----------------
__global__ void prep_w(const float* __restrict__ W0, const float* __restrict__ W1,
                       const float* __restrict__ W2, const float* __restrict__ W3,
                       const float* __restrict__ W4, const float* __restrict__ W5,
                       const float* __restrict__ W6, const float* __restrict__ W7,
                       short* __restrict__ ws) {
  const float* W[8] = {W0, W1, W2, W3, W4, W5, W6, W7};
  int t = blockIdx.x * 256 + threadIdx.x;
  int lane = t & 63, fragid = (t >> 6) & 7, mat = t >> 9;
  const float* Wm = W[mat];
  int ct = fragid >> 1, kh = fragid & 1;
  int wcol = ct * 16 + (lane & 15);
  int k0 = kh * 32 + ((lane >> 4) << 3);
  bf16x8 vh, vl;
#pragma unroll
  for (int j = 0; j < 8; ++j) {
    short h, l;
    split2(Wm[(k0 + j) * 64 + wcol], h, l);
    vh[j] = h; vl[j] = l;
  }
  size_t base = ((size_t)(mat * 16) + fragid) * 512 + lane * 8;
  *(bf16x8*)(ws + base) = vh;
  *(bf16x8*)(ws + base + 4096) = vl;
}

struct BF { bf16x8 h[4][2], l[4][2]; };

static __device__ __forceinline__ void loadB(const short* __restrict__ ws, int mat, int lane,
                                             BF& B) {
#pragma unroll
  for (int ct = 0; ct < 4; ++ct)
#pragma unroll
    for (int kh = 0; kh < 2; ++kh) {
      B.h[ct][kh] = *(const bf16x8*)(ws + ((size_t)(mat * 16) + ct * 2 + kh) * 512 + lane * 8);
      B.l[ct][kh] = *(const bf16x8*)(ws + ((size_t)(mat * 16 + 8) + ct * 2 + kh) * 512 + lane * 8);
    }
}

// fenced MFMA cluster (R13-proven)
static __device__ __forceinline__ void cluster(const bf16x8 (&ah)[2], const bf16x8 (&al)[2],
                                               const BF& B, f32x4 (&acc)[4]) {
  __builtin_amdgcn_sched_barrier(0);
#pragma unroll
  for (int ct = 0; ct < 4; ++ct)
#pragma unroll
    for (int kh = 0; kh < 2; ++kh) {
      acc[ct] = MFMA(ah[kh], B.h[ct][kh], acc[ct]);
      acc[ct] = MFMA(al[kh], B.h[ct][kh], acc[ct]);
      acc[ct] = MFMA(ah[kh], B.l[ct][kh], acc[ct]);
    }
  __builtin_amdgcn_sched_barrier(0);
  NOPS;
}

// swizzled stride-64 plane load/store (HW-verified R6; plane = 8192 B)
static __device__ __forceinline__ void ldM(const short* __restrict__ M, int ph, int arow,
                                           int lane, bf16x8 (&ah)[2], bf16x8 (&al)[2]) {
  int swz = (arow & 7) << 4;
#pragma unroll
  for (int kh = 0; kh < 2; ++kh) {
    int ab = (arow * 128 + kh * 64 + ((lane >> 4) << 4)) ^ swz;
    ah[kh] = *(const bf16x8*)((const char*)M + ph * 8192 + ab);
    al[kh] = *(const bf16x8*)((const char*)M + (ph + 1) * 8192 + ab);
  }
}
static __device__ __forceinline__ void stM(short* __restrict__ M, int p, int n, int w, float x) {
  short h, l;
  split2(x, h, l);
  int ab = (n * 128 + w * 2) ^ ((n & 7) << 4);
  *(short*)((char*)M + p * 8192 + ab) = h;
  *(short*)((char*)M + (p + 1) * 8192 + ab) = l;
}

// ---------------- fused kernel: 64 rows/block, 256 threads ----------------
// ksc folded into x1 staging; c2a=kp/ksc folded into mids; epilogue = bare store.
__global__ __launch_bounds__(256, 2) void fused_tp(
    const float* __restrict__ x1, const float* __restrict__ edge,
    const float* __restrict__ tp, const float* __restrict__ node,
    const short* __restrict__ ws, float* __restrict__ out) {
  __shared__ short lds_s[8 * 4096];   // 8 swizzled half-planes, 64 KB
  __shared__ float cst[64 * 6];       // e0,e1x,e1y,e1z,c2a
  const int t = threadIdx.x;
  const int R0 = blockIdx.x * 64;

  // ---- phase 0: stage ksc-scaled x1 -> planes s(0,1) vx(2,3) vy(4,5) vz(6,7) ----
  {
    int c = t;
    int plane_hi, u;
    if (c < 64) { plane_hi = 0; u = c; }
    else { int q = c - 64; u = q / 3; int m = q - u * 3; plane_hi = 2 + 2 * m; }
    char* phi = (char*)lds_s + plane_hi * 8192;
    char* plo = phi + 8192;
    const float* xc = x1 + (size_t)R0 * 256 + c;
#pragma unroll 8
    for (int i = 0; i < 64; ++i) {
      float ksc = 0.125f * node[R0 + i];
      short h, l;
      split2(ksc * xc[(size_t)i * 256], h, l);
      int ab = (i * 128 + u * 2) ^ ((i & 7) << 4);
      *(short*)(phi + ab) = h;
      *(short*)(plo + ab) = l;
    }
    if (t < 64) {
      f32x4 e = *(const f32x4*)(edge + (size_t)(R0 + t) * 4);
      float a = node[R0 + t];
      float* cr = cst + t * 6;
      cr[0] = e[0]; cr[1] = e[1]; cr[2] = e[2]; cr[3] = e[3];
      cr[4] = 0.08838834764831845f * a;  // c2a = kp/ksc
    }
  }
  __syncthreads();

  const int lane = t & 63;
  const int wid = t >> 6;
  const int r0 = wid * 16;
  const int lg = lane >> 4;
  const int arow = r0 + (lane & 15);
  const f32x4 z = {0.f, 0.f, 0.f, 0.f};

  // output accumulators (final values, no epilogue scaling)
  f32x4 outS[4], outV[3][4], s0v[4], v0v[3][4];
#pragma unroll
  for (int ct = 0; ct < 4; ++ct) { outS[ct] = z; s0v[ct] = z; }
#pragma unroll
  for (int m = 0; m < 3; ++m)
#pragma unroll
    for (int ct = 0; ct < 4; ++ct) { outV[m][ct] = z; v0v[m][ct] = z; }

  // ---- stage 1: 8 clusters, 4 B-loads (each mat serves its clusters consecutively) ----
  {
    BF B;
    bf16x8 ah[2], al[2];
    loadB(ws, 0, lane, B);                       // W_sc_s
    ldM(lds_s, 0, arow, lane, ah, al);           // s' = ksc*s
    cluster(ah, al, B, outS);                    // += ksc*scs
    loadB(ws, 1, lane, B);                       // W_lin0_s
    cluster(ah, al, B, s0v);                     // s0' = ksc*s0
    loadB(ws, 2, lane, B);                       // W_sc_v (x3 reuse)
#pragma unroll
    for (int m = 0; m < 3; ++m) {
      ldM(lds_s, 2 + 2 * m, arow, lane, ah, al);
      cluster(ah, al, B, outV[m]);               // += ksc*scv_m
    }
    loadB(ws, 3, lane, B);                       // W_lin0_v (x3 reuse)
#pragma unroll
    for (int m = 0; m < 3; ++m) {
      ldM(lds_s, 2 + 2 * m, arow, lane, ah, al);
      cluster(ah, al, B, v0v[m]);                // v0' = ksc*v0
    }
  }
  __syncthreads();

  // ---- phase 2a: mids kp*mA -> (0,1), kp*e1m*mB -> (2,3),(4,5),(6,7) ----
#pragma unroll
  for (int reg = 0; reg < 4; ++reg) {
    int n = r0 + (lg << 2) + reg;
    const float* cr = cst + n * 6;
    float e0 = cr[0], e1x = cr[1], e1y = cr[2], e1z = cr[3], c2a = cr[4];
    const float* tr = tp + (size_t)(R0 + n) * 256;
#pragma unroll
    for (int ct = 0; ct < 4; ++ct) {
      int w = ct * 16 + (lane & 15);
      float t0 = c2a * s0v[ct][reg];             // kp*s0
      float wa = tr[w], wb = tr[64 + w];
      stM(lds_s, 0, n, w, wa * t0 * e0);
      float bmul = wb * t0;
      stM(lds_s, 2, n, w, bmul * e1x);
      stM(lds_s, 4, n, w, bmul * e1y);
      stM(lds_s, 6, n, w, bmul * e1z);
    }
  }
  __syncthreads();

  // ---- stage 2a: WA on mA -> outS ; WB on mB_m -> outV[m] (2 loads, 4 clusters) ----
  {
    BF B;
    bf16x8 ah[2], al[2];
    loadB(ws, 4, lane, B);                       // W_lin_A
    ldM(lds_s, 0, arow, lane, ah, al);
    cluster(ah, al, B, outS);
    loadB(ws, 6, lane, B);                       // W_lin_B (x3 reuse)
#pragma unroll
    for (int m = 0; m < 3; ++m) {
      ldM(lds_s, 2 + 2 * m, arow, lane, ah, al);
      cluster(ah, al, B, outV[m]);
    }
  }
  __syncthreads();

  // ---- phase 2b: kp*mD -> (0,1), kp*mC_m -> (2,3),(4,5),(6,7) ----
#pragma unroll
  for (int reg = 0; reg < 4; ++reg) {
    int n = r0 + (lg << 2) + reg;
    const float* cr = cst + n * 6;
    float e0 = cr[0], e1x = cr[1], e1y = cr[2], e1z = cr[3], c2a = cr[4];
    const float* tr = tp + (size_t)(R0 + n) * 256;
#pragma unroll
    for (int ct = 0; ct < 4; ++ct) {
      int w = ct * 16 + (lane & 15);
      float kv0 = c2a * v0v[0][ct][reg];
      float kv1 = c2a * v0v[1][ct][reg];
      float kv2 = c2a * v0v[2][ct][reg];
      float wc = tr[128 + w], wd = tr[192 + w];
      stM(lds_s, 0, n, w, wd * (kv0 * e1x + kv1 * e1y + kv2 * e1z) * 0.5773502691896258f);
      stM(lds_s, 2, n, w, wc * kv0 * e0);
      stM(lds_s, 4, n, w, wc * kv1 * e0);
      stM(lds_s, 6, n, w, wc * kv2 * e0);
    }
  }
  __syncthreads();

  // ---- stage 2b: WD on mD -> outS ; WC on mC_m -> outV[m] (2 loads, 4 clusters) ----
  {
    BF B;
    bf16x8 ah[2], al[2];
    loadB(ws, 5, lane, B);                       // W_lin_D
    ldM(lds_s, 0, arow, lane, ah, al);
    cluster(ah, al, B, outS);
    loadB(ws, 7, lane, B);                       // W_lin_C (x3 reuse)
#pragma unroll
    for (int m = 0; m < 3; ++m) {
      ldM(lds_s, 2 + 2 * m, arow, lane, ah, al);
      cluster(ah, al, B, outV[m]);
    }
  }

  // ---- epilogue: bare store ----
#pragma unroll
  for (int reg = 0; reg < 4; ++reg) {
    int n = r0 + (lg << 2) + reg;
    float* orow = out + (size_t)(R0 + n) * 256;
#pragma unroll
    for (int ct = 0; ct < 4; ++ct) {
      int w = ct * 16 + (lane & 15);
      orow[w] = outS[ct][reg];
      float* vp = orow + 64 + 3 * w;
      vp[0] = outV[0][ct][reg];
      vp[1] = outV[1][ct][reg];
      vp[2] = outV[2][ct][reg];
    }
  }
}

extern "C" void kernel_launch(void* const* d_in, const int* in_sizes, int n_in,
                              void* d_out, int out_size, void* d_ws, size_t ws_size,
                              hipStream_t stream) {
  const float* x1   = (const float*)d_in[0];
  const float* edge = (const float*)d_in[1];
  const float* tp   = (const float*)d_in[2];
  const float* node = (const float*)d_in[3];
  short* ws = (short*)d_ws;  // 128 KiB
  int n = in_sizes[0] / 256;

  // mats: 0=W_sc_s 1=W_lin0_s 2=W_sc_v 3=W_lin0_v 4=W_lin_A 5=W_lin_D 6=W_lin_B 7=W_lin_C
  prep_w<<<16, 256, 0, stream>>>(
      (const float*)d_in[6], (const float*)d_in[4],
      (const float*)d_in[7], (const float*)d_in[5],
      (const float*)d_in[8], (const float*)d_in[9],
      (const float*)d_in[10], (const float*)d_in[11], ws);

  fused_tp<<<n / 64, 256, 0, stream>>>(x1, edge, tp, node, ws, (float*)d_out);
}